// Round 8
// baseline (241.572 us; speedup 1.0000x reference)
//
#include <hip/hip_runtime.h>
#include <stdint.h>

typedef unsigned short u16;
typedef __attribute__((ext_vector_type(8))) __bf16 bf16x8;
typedef __attribute__((ext_vector_type(4))) float f32x4;

__device__ __forceinline__ u16 f2bf(float f) {
  unsigned u = __float_as_uint(f);
  u += 0x7FFF + ((u >> 16) & 1);   // RNE
  return (u16)(u >> 16);
}

__device__ __forceinline__ float bf2f(u16 h) {
  return __uint_as_float(((unsigned)h) << 16);
}

__device__ __forceinline__ void llds16(const u16* g, u16* l) {
  __builtin_amdgcn_global_load_lds(
      (const __attribute__((address_space(1))) void*)g,
      (__attribute__((address_space(3))) void*)l, 16, 0, 0);
}

// ---------------------------------------------------------------------------
// fused cast fp32 -> bf16 for x | wq | wk | wv + zero the lsum accumulator
// ---------------------------------------------------------------------------
__global__ __launch_bounds__(256) void cast_all(
    const float* __restrict__ x, const float* __restrict__ wq,
    const float* __restrict__ wk, const float* __restrict__ wv,
    u16* __restrict__ xb, u16* __restrict__ wb, float* __restrict__ lsum) {
  int i = blockIdx.x * 256 + threadIdx.x;
  if (i < 8192) lsum[i] = 0.f;        // softmax-denominator accumulator
  const float* src; u16* dst; int off;
  if (i < 2097152)      { src = x;  dst = xb;            off = i; }
  else if (i < 2359296) { src = wq; dst = wb;            off = i - 2097152; }
  else if (i < 2621440) { src = wk; dst = wb + 1048576;  off = i - 2359296; }
  else                  { src = wv; dst = wb + 2097152;  off = i - 2621440; }
  float4 f = ((const float4*)src)[off];
  ushort4 o;
  o.x = f2bf(f.x); o.y = f2bf(f.y); o.z = f2bf(f.z); o.w = f2bf(f.w);
  ((ushort4*)dst)[off] = o;
}

// ---------------------------------------------------------------------------
// QKV GEMM (proven R5/R7 core): C[8192,3072] = xb[8192,1024] @ wb[3072,1024]^T
// 128x128 tile, BK=64, 4 waves (2x2), 4x4 mfma_f32_16x16x32_bf16 per wave.
// global_load_lds width-16; chunk-XOR swizzle (slot = chunk ^ (row&7)) ->
// SQ_LDS_BANK_CONFLICT == 0 measured.  Cols <2048 -> qk; >=2048 -> vt^T.
// ---------------------------------------------------------------------------
__global__ __launch_bounds__(256) void gemm_qkv(
    const u16* __restrict__ A, int lda,
    const u16* __restrict__ B, int ldb,
    u16* __restrict__ C, int ldc, int K, u16* __restrict__ vt) {
  const int t = threadIdx.x;
  const int rowbase = blockIdx.x * 128;
  const int colbase = blockIdx.y * 128;

  __shared__ u16 As[8192];   // [128][64] u16, chunk-swizzled
  __shared__ u16 Bs[8192];

  const int lane = t & 63;
  const int wv = t >> 6;
  const int wr = wv >> 1;
  const int wc = wv & 1;
  const int quad = lane >> 4;
  const int lr = lane & 15;

  f32x4 acc[4][4];
  const f32x4 zero = {0.f, 0.f, 0.f, 0.f};
#pragma unroll
  for (int i = 0; i < 4; ++i)
#pragma unroll
    for (int j = 0; j < 4; ++j) acc[i][j] = zero;

  {
    const int csw = (t & 7) ^ ((t >> 3) & 7);
    const u16* ga = A + (long long)(rowbase + (t >> 3)) * lda + csw * 8;
    const u16* gb = B + (long long)(colbase + (t >> 3)) * ldb + csw * 8;
    const long long ra = 32LL * lda, rb = 32LL * ldb;
    u16* la = As + t * 8;
    u16* lb = Bs + t * 8;

    const int m7 = lr & 7;
    const int a_base = (wr * 64 + lr) * 64 + ((quad ^ m7) * 8);
    const int b_base = (wc * 64 + lr) * 64 + ((quad ^ m7) * 8);

    for (int k0 = 0; k0 < K; k0 += 64) {
      __syncthreads();
#pragma unroll
      for (int i = 0; i < 4; ++i) {
        llds16(ga + k0 + i * ra, la + i * 2048);
        llds16(gb + k0 + i * rb, lb + i * 2048);
      }
      __syncthreads();
#pragma unroll
      for (int ks = 0; ks < 2; ++ks) {
        const int ko = ks ? 32 : 0;
        bf16x8 af[4], bfv[4];
#pragma unroll
        for (int tm = 0; tm < 4; ++tm)
          af[tm] = *(const bf16x8*)(As + ((a_base + tm * 1024) ^ ko));
#pragma unroll
        for (int tn = 0; tn < 4; ++tn)
          bfv[tn] = *(const bf16x8*)(Bs + ((b_base + tn * 1024) ^ ko));
#pragma unroll
        for (int tm = 0; tm < 4; ++tm)
#pragma unroll
          for (int tn = 0; tn < 4; ++tn)
            acc[tm][tn] = __builtin_amdgcn_mfma_f32_16x16x32_bf16(
                af[tm], bfv[tn], acc[tm][tn], 0, 0, 0);
      }
    }
  }

  // C/D layout (m89/m91): col = lane&15, row = (lane>>4)*4 + reg
  if (colbase >= 2048) {
    // V block: write transposed to vt[b][e][s]; 4 regs = 4 consecutive s
#pragma unroll
    for (int tm = 0; tm < 4; ++tm) {
      int s0 = rowbase + wr * 64 + tm * 16 + quad * 4;
      int b = s0 >> 11;
      int sl = s0 & 2047;
#pragma unroll
      for (int tn = 0; tn < 4; ++tn) {
        int e = colbase - 2048 + wc * 64 + tn * 16 + lr;
        ushort4 o;
        o.x = f2bf(acc[tm][tn][0]);
        o.y = f2bf(acc[tm][tn][1]);
        o.z = f2bf(acc[tm][tn][2]);
        o.w = f2bf(acc[tm][tn][3]);
        *(ushort4*)(vt + ((long long)(b * 1024 + e)) * 2048 + sl) = o;
      }
    }
    return;
  }

#pragma unroll
  for (int tm = 0; tm < 4; ++tm)
#pragma unroll
    for (int r = 0; r < 4; ++r) {
      const int grow = rowbase + wr * 64 + tm * 16 + quad * 4 + r;
#pragma unroll
      for (int tn = 0; tn < 4; ++tn) {
        const int gcol = colbase + wc * 64 + tn * 16 + lr;
        C[(long long)grow * ldc + gcol] = f2bf(acc[tm][tn][r]);
      }
    }
}

// ---------------------------------------------------------------------------
// Attention GEMMs, 64x128 tile (fine-grained: 2-4x more blocks than the
// 128-tile versions -> better CU overlap; R7 showed scores/PV at ~257 TF
// vs QKV 780 from occupancy starvation at ~2 blocks/CU).
// 256 threads = 4 waves in 1x4: wave w owns rows 0..63 x cols w*32..+32
// via 4x2 mfma_f32_16x16x32_bf16.  Same XOR-swizzled LDS (conflict-free).
// MODE 1: exp-scores -> tri decode (272 tiles/batch causal), exp(s*scale),
//         causal -> 0, row sums via shuffle + atomicAdd into lsum
// MODE 2: PV -> fp32 * rcp(lsum[row]), Keff = rowbase+64, longest-first
// ---------------------------------------------------------------------------
template<int MODE>
__global__ __launch_bounds__(256) void gemm_att(
    const u16* __restrict__ A, long long sA, int lda,
    const u16* __restrict__ B, long long sB, int ldb,
    void* __restrict__ Cp, long long sC, int ldc,
    int K, float scale, float* __restrict__ lsum,
    const int* __restrict__ causalp) {
  const int t = threadIdx.x;
  const int causal = causalp[0];

  int rt, ct;
  if (MODE == 1) {
    int x = blockIdx.x;               // grid.x = 512
    if (causal) {
      if (x >= 272) return;           // upper tiles never needed
      // tri decode: pair p = rt>>1 has 2 rows x (p+1) cols; cum = p(p+1)
      int p = (int)((sqrtf(4.0f * x + 1.0f) - 1.0f) * 0.5f);
      while ((p + 1) * (p + 2) <= x) ++p;
      while (p * (p + 1) > x) --p;
      int rem = x - p * (p + 1);
      int hi = (rem >= p + 1) ? 1 : 0;
      rt = 2 * p + hi;
      ct = rem - hi * (p + 1);
    } else {
      rt = x >> 4; ct = x & 15;       // all 512 tiles
    }
  } else {
    rt = 31 - blockIdx.x;             // longest Keff first
    ct = blockIdx.y;
  }

  const int rowbase = rt * 64;
  const int colbase = ct * 128;
  const u16* Ab = A + (long long)blockIdx.z * sA;
  const u16* Bb = B + (long long)blockIdx.z * sB;

  int Keff = K;
  if (MODE == 2 && causal) Keff = min(K, rowbase + 64);

  __shared__ u16 As[4096];   // [64][64] u16, chunk-swizzled
  __shared__ u16 Bs[8192];   // [128][64]

  const int lane = t & 63;
  const int w = t >> 6;          // wave 0..3 -> col strip w*32
  const int quad = lane >> 4;
  const int lr = lane & 15;

  f32x4 acc[4][2];
  const f32x4 zero = {0.f, 0.f, 0.f, 0.f};
#pragma unroll
  for (int i = 0; i < 4; ++i)
#pragma unroll
    for (int j = 0; j < 2; ++j) acc[i][j] = zero;

  {
    const int csw = (t & 7) ^ ((t >> 3) & 7);
    const u16* ga = Ab + (long long)(rowbase + (t >> 3)) * lda + csw * 8;
    const u16* gb = Bb + (long long)(colbase + (t >> 3)) * ldb + csw * 8;
    const long long ra = 32LL * lda, rb = 32LL * ldb;
    u16* la = As + t * 8;
    u16* lb = Bs + t * 8;

    const int m7 = lr & 7;
    const int a_base = lr * 64 + ((quad ^ m7) * 8);             // +tm*1024
    const int b_base = (w * 32 + lr) * 64 + ((quad ^ m7) * 8);  // +tn*1024

    for (int k0 = 0; k0 < Keff; k0 += 64) {
      __syncthreads();
      llds16(ga + k0, la);
      llds16(ga + k0 + ra, la + 2048);
#pragma unroll
      for (int i = 0; i < 4; ++i)
        llds16(gb + k0 + i * rb, lb + i * 2048);
      __syncthreads();
#pragma unroll
      for (int ks = 0; ks < 2; ++ks) {
        const int ko = ks ? 32 : 0;
        bf16x8 af[4], bfv[2];
#pragma unroll
        for (int tm = 0; tm < 4; ++tm)
          af[tm] = *(const bf16x8*)(As + ((a_base + tm * 1024) ^ ko));
#pragma unroll
        for (int tn = 0; tn < 2; ++tn)
          bfv[tn] = *(const bf16x8*)(Bs + ((b_base + tn * 1024) ^ ko));
#pragma unroll
        for (int tm = 0; tm < 4; ++tm)
#pragma unroll
          for (int tn = 0; tn < 2; ++tn)
            acc[tm][tn] = __builtin_amdgcn_mfma_f32_16x16x32_bf16(
                af[tm], bfv[tn], acc[tm][tn], 0, 0, 0);
      }
    }
  }

  // epilogue; C/D: col = lr, row = quad*4 + reg
#pragma unroll
  for (int tm = 0; tm < 4; ++tm)
#pragma unroll
    for (int r = 0; r < 4; ++r) {
      const int grow = rowbase + tm * 16 + quad * 4 + r;
      float li, rsum = 0.f;
      if (MODE == 2) li = __builtin_amdgcn_rcpf(lsum[blockIdx.z * 2048 + grow]);
#pragma unroll
      for (int tn = 0; tn < 2; ++tn) {
        const int gcol = colbase + w * 32 + tn * 16 + lr;
        float val = acc[tm][tn][r];
        if (MODE == 1) {
          u16* C = (u16*)Cp + (long long)blockIdx.z * sC;
          float ex = (causal && gcol > grow) ? 0.f : __expf(val * scale);
          C[(long long)grow * ldc + gcol] = f2bf(ex);
          rsum += ex;
        } else {
          float* C = (float*)Cp + (long long)blockIdx.z * sC;
          C[(long long)grow * ldc + gcol] = val * li;
        }
      }
      if (MODE == 1) {
        // reduce over the 16 col-lanes of this row, 1 atomic per wave-row
#pragma unroll
        for (int o = 8; o > 0; o >>= 1) rsum += __shfl_xor(rsum, o, 64);
        if (lr == 0)
          atomicAdd(&lsum[blockIdx.z * 2048 + grow], rsum);
      }
    }
}

// ---------------------------------------------------------------------------
extern "C" void kernel_launch(void* const* d_in, const int* in_sizes, int n_in,
                              void* d_out, int out_size, void* d_ws, size_t ws_size,
                              hipStream_t stream) {
  const float* x  = (const float*)d_in[0];
  const float* wq = (const float*)d_in[1];
  const float* wk = (const float*)d_in[2];
  const float* wv = (const float*)d_in[3];
  const int* causal = (const int*)d_in[4];
  float* out = (float*)d_out;

  // workspace layout (bytes):
  //   xb 0..16,777,216   wb ..23,068,672   qk ..56,623,104
  //   vt ..73,400,320    sb ..106,954,752  lsum ..106,987,520
  char* ws = (char*)d_ws;
  u16* xb = (u16*)(ws);               // [8192][1024] bf16 x
  u16* wb = (u16*)(ws + 16777216);    // [3072][1024] bf16 Wq|Wk|Wv
  u16* qk = (u16*)(ws + 23068672);    // [8192][2048] bf16 Q|K
  u16* vt = (u16*)(ws + 56623104);    // [4][1024][2048] bf16 V^T
  u16* sb = (u16*)(ws + 73400320);    // [4][2048][2048] bf16 exp-scores
  float* lsum = (float*)(ws + 106954752);  // [4][2048] softmax denominators

  // casts (x, wq, wk, wv -> bf16) + lsum zero-init, one launch
  cast_all<<<11264, 256, 0, stream>>>(x, wq, wk, wv, xb, wb, lsum);

  // QKV: [8192 x 3072] = xb @ wb^T ; Q,K -> qk, V -> vt (transposed)
  gemm_qkv<<<dim3(64, 24), 256, 0, stream>>>(
      xb, 1024, wb, 1024, qk, 2048, 1024, vt);

  // exp-scores per batch: P' = exp((Q @ K^T)/32), causal -> 0, bf16;
  // 64x128 tiles, tri decode; row sums -> lsum via atomics
  gemm_att<1><<<dim3(512, 1, 4), 256, 0, stream>>>(
      qk, 2048LL * 2048, 2048, qk + 1024, 2048LL * 2048, 2048,
      sb, 2048LL * 2048, 2048, 1024, 0.03125f, lsum, causal);

  // out per batch: [2048 x 1024] = (P' @ (V^T)^T) * rcp(lsum) -> fp32
  gemm_att<2><<<dim3(32, 8, 4), 256, 0, stream>>>(
      sb, 2048LL * 2048, 2048, vt, 1024LL * 2048, 2048,
      out, 2048LL * 1024, 1024, 2048, 1.0f, lsum, causal);
}